// Round 16
// baseline (148.241 us; speedup 1.0000x reference)
//
#include <hip/hip_runtime.h>
#include <hip/hip_bf16.h>
#include <math.h>

#define N_ROWS  100000
#define NT_ROW  6250            // 16-row tiles, exact: 6250*16 = 100000

typedef __attribute__((ext_vector_type(8))) short bf16x8;   // 4 VGPR A/B frag
typedef __attribute__((ext_vector_type(4))) float f32x4;    // C/D frag

__device__ __forceinline__ float silu_f(float v) {
    return v * (1.0f / (1.0f + __expf(-v)));
}
__device__ __forceinline__ short f2bf(float f) {
    union { __hip_bfloat16 h; short s; } u;
    u.h = __float2bfloat16(f);          // RNE convert
    return u.s;
}
// async global->LDS: per-lane global src, wave-uniform LDS base + lane*16B dest
__device__ __forceinline__ void stage16(const void* g, void* l) {
    __builtin_amdgcn_global_load_lds(
        (const __attribute__((address_space(1))) unsigned int*)g,
        (__attribute__((address_space(3))) unsigned int*)l,
        16, 0, 0);
}

// ---- pre-kernel: fragment-packed weights (unchanged, verified) -------------
// wTf[(t*8+p)*1024 B + lane*16 B] = B-fragment for col-tile t, K-pass p.
__global__ __launch_bounds__(64)
void prep_wT(const float* __restrict__ w1_s, const float* __restrict__ w1_v,
             unsigned short* __restrict__ wTf)
{
    const int tp = blockIdx.x;               // 0..159 = t*8 + p
    const int t = tp >> 3, p = tp & 7;
    const int lane = threadIdx.x;            // 0..63
    const int l15 = lane & 15, lq = lane >> 4;
    const float* src  = (t < 8) ? w1_s : w1_v;
    const int    strd = (t < 8) ? 128 : 64;
    const int    scol = (t < 8) ? (t * 16 + l15) : (((t - 8) & 3) * 16 + l15);
    const int    k0   = 32 * p + 8 * lq;
    unsigned short o[8];
    #pragma unroll
    for (int e = 0; e < 8; ++e)
        o[e] = (unsigned short)f2bf(src[(k0 + e) * strd + scol]);
    *(ushort4*)(wTf + (size_t)tp * 512 + lane * 8)     = make_ushort4(o[0], o[1], o[2], o[3]);
    *(ushort4*)(wTf + (size_t)tp * 512 + lane * 8 + 4) = make_ushort4(o[4], o[5], o[6], o[7]);
}

// ---- main: 1 block = 16 rows x 320 cols; x AND B staged via global_load_lds.
// Main loop has NO vector loads -> MFMAs wait on no vmcnt; the only vmcnt
// wait is the counted vmcnt(7) at pass top for stages issued 2 iters earlier
// (~1400cy cover > 900cy HBM latency). B re-fetch drops 4x (per block).
// BUGFIX vs r15: B stage source must be PER-LANE (+ lane*8 shorts = lane*16B);
// global_load_lds's uniform part is the LDS dest, not the global src.
__global__ __launch_bounds__(256, 2)
void ndr_mfma_kernel(const float* __restrict__ x,
                     const unsigned short* __restrict__ wTf,
                     const float* __restrict__ w2_s,
                     const float* __restrict__ w2_v,
                     float* __restrict__ out)
{
    __shared__ float  xbuf[2][16][128];      // 16 KB  (pass-slice of 16 rows)
    __shared__ short  Bbuf[2][20][512];      // 40 KB  (20 frags x 1KB)
    __shared__ float4 red[4][16];            // 1 KB cross-wave partials

    const int lane = threadIdx.x & 63;
    const int wid  = threadIdx.x >> 6;       // wave 0..3
    const int l15  = lane & 15, lq = lane >> 4, r7 = l15 & 7;
    const long long n0 = (long long)blockIdx.x * 16;

    const float w2sv = w2_s[16 * wid + l15];
    const float w2vv = w2_v[16 * wid + l15];

    // x staging map (verified r12 scheme): wave w issues chunks j=2w,2w+1;
    // chunk j covers rows 2j (lanes 0-31) / 2j+1 (lanes 32-63), slot=lane&31,
    // source segment g = slot ^ (row&7)  (write-side inverse swizzle).
    const int sub = lane >> 5, slot = lane & 31;
    const float* sp[2];
    int sstep[2];
    #pragma unroll
    for (int jj = 0; jj < 2; ++jj) {
        const int j   = 2 * wid + jj;
        const int row = 2 * j + sub;
        const int g   = slot ^ (row & 7);
        const int isxs = (g < 8);
        sstep[jj] = isxs ? 32 : 96;
        sp[jj] = x + (n0 + row) * 1024 + (isxs ? 4 * g : 256 + 4 * (g - 8));
    }

    f32x4 acc[5];
    #pragma unroll
    for (int t = 0; t < 5; ++t) acc[t] = (f32x4){0.f, 0.f, 0.f, 0.f};

    // issue the 7 stages (2 x + 5 B) for pass p into buffer b
    #define STAGE_PASS(p_, b_)                                                \
        do {                                                                  \
            stage16(sp[0] + (p_) * sstep[0], &xbuf[b_][0][0] + (2*wid    )*256); \
            stage16(sp[1] + (p_) * sstep[1], &xbuf[b_][0][0] + (2*wid + 1)*256); \
            _Pragma("unroll")                                                 \
            for (int u = 0; u < 5; ++u) {                                     \
                const int t_ = wid + 4 * u;                                   \
                stage16(wTf + (size_t)(t_ * 8 + (p_)) * 512 + lane * 8,       \
                        &Bbuf[b_][t_][0]);                                    \
            }                                                                 \
        } while (0)

    // prologue: pass 0 -> buf0, pass 1 -> buf1 (grouped: pass 0's 7 first)
    STAGE_PASS(0, 0);
    STAGE_PASS(1, 1);

    #pragma unroll 1
    for (int p = 0; p < 8; ++p) {
        // pass-p stages (issued 2 iters ago) landed; newest 7 (pass p+1) stay
        if (p < 7) asm volatile("s_waitcnt vmcnt(7)" ::: "memory");
        else       asm volatile("s_waitcnt vmcnt(0)" ::: "memory");
        __builtin_amdgcn_s_barrier();

        // ---- LDS reads (lgkm domain only) ----
        const float* rb = &xbuf[p & 1][l15][0];
        float4 s0 = *(const float4*)(rb + 4 * ((2 * lq    ) ^ r7));
        float4 s1 = *(const float4*)(rb + 4 * ((2 * lq + 1) ^ r7));
        float4 v0 = *(const float4*)(rb + 4 * ((8 + 6 * lq + 0) ^ r7));
        float4 v1 = *(const float4*)(rb + 4 * ((8 + 6 * lq + 1) ^ r7));
        float4 v2 = *(const float4*)(rb + 4 * ((8 + 6 * lq + 2) ^ r7));
        float4 v3 = *(const float4*)(rb + 4 * ((8 + 6 * lq + 3) ^ r7));
        float4 v4 = *(const float4*)(rb + 4 * ((8 + 6 * lq + 4) ^ r7));
        float4 v5 = *(const float4*)(rb + 4 * ((8 + 6 * lq + 5) ^ r7));
        bf16x8 bf[5];
        #pragma unroll
        for (int u = 0; u < 5; ++u)
            bf[u] = *(const bf16x8*)&Bbuf[p & 1][wid + 4 * u][lane * 8];

        // all my LDS reads done; all waves done -> safe to overwrite buffer
        asm volatile("s_waitcnt lgkmcnt(0)" ::: "memory");
        __builtin_amdgcn_s_barrier();

        if (p + 2 < 8) STAGE_PASS(p + 2, p & 1);

        // ---- cvt + MFMA (registers only; no memory waits) ----
        const float xs[8]  = {s0.x, s0.y, s0.z, s0.w, s1.x, s1.y, s1.z, s1.w};
        const float xv[24] = {v0.x, v0.y, v0.z, v0.w, v1.x, v1.y, v1.z, v1.w,
                              v2.x, v2.y, v2.z, v2.w, v3.x, v3.y, v3.z, v3.w,
                              v4.x, v4.y, v4.z, v4.w, v5.x, v5.y, v5.z, v5.w};
        bf16x8 a_s, a_v0, a_v1, a_v2;        // A[row=l15][k=32p+8lq+e]
        #pragma unroll
        for (int e = 0; e < 8; ++e) {
            a_s[e]  = f2bf(xs[e]);
            a_v0[e] = f2bf(xv[3 * e + 0]);
            a_v1[e] = f2bf(xv[3 * e + 1]);
            a_v2[e] = f2bf(xv[3 * e + 2]);
        }
        acc[0] = __builtin_amdgcn_mfma_f32_16x16x32_bf16(a_s,  bf[0], acc[0], 0, 0, 0);
        acc[1] = __builtin_amdgcn_mfma_f32_16x16x32_bf16(a_s,  bf[1], acc[1], 0, 0, 0);
        acc[2] = __builtin_amdgcn_mfma_f32_16x16x32_bf16(a_v0, bf[2], acc[2], 0, 0, 0);
        acc[3] = __builtin_amdgcn_mfma_f32_16x16x32_bf16(a_v1, bf[3], acc[3], 0, 0, 0);
        acc[4] = __builtin_amdgcn_mfma_f32_16x16x32_bf16(a_v2, bf[4], acc[4], 0, 0, 0);
    }
    #undef STAGE_PASS

    // ---- epilogue: silu-gate + layer 2 (r12-verified) ----------------------
    const float inv_in = 0.0625f, inv_h = 0.125f;
    #pragma unroll
    for (int j = 0; j < 4; ++j) {
        float hs = acc[0][j] * inv_in;       // scalars col 16wid+l15
        float hg = acc[1][j] * inv_in;       // gates   col 16wid+l15
        float gg = silu_f(hg);
        float ps  = silu_f(hs) * w2sv;
        float pv0 = gg * (acc[2][j] * inv_in) * w2vv;
        float pv1 = gg * (acc[3][j] * inv_in) * w2vv;
        float pv2 = gg * (acc[4][j] * inv_in) * w2vv;
        #pragma unroll
        for (int off = 1; off <= 8; off <<= 1) {   // reduce over 16 l15 lanes
            ps  += __shfl_xor(ps,  off, 64);
            pv0 += __shfl_xor(pv0, off, 64);
            pv1 += __shfl_xor(pv1, off, 64);
            pv2 += __shfl_xor(pv2, off, 64);
        }
        if (l15 == 0)
            red[wid][lq * 4 + j] = make_float4(ps, pv0, pv1, pv2);
    }
    __syncthreads();
    if (wid == 0 && lane < 16) {             // lane = row within tile
        float4 a = red[0][lane], b = red[1][lane],
               c = red[2][lane], d = red[3][lane];
        *(float4*)(out + (n0 + lane) * 4) =
            make_float4((a.x + b.x + c.x + d.x) * inv_h,
                        (a.y + b.y + c.y + d.y) * inv_h,
                        (a.z + b.z + c.z + d.z) * inv_h,
                        (a.w + b.w + c.w + d.w) * inv_h);
    }
}

extern "C" void kernel_launch(void* const* d_in, const int* in_sizes, int n_in,
                              void* d_out, int out_size, void* d_ws, size_t ws_size,
                              hipStream_t stream) {
    const float* x    = (const float*)d_in[0];
    const float* w1_s = (const float*)d_in[1];
    const float* w1_v = (const float*)d_in[2];
    const float* w2_s = (const float*)d_in[3];
    const float* w2_v = (const float*)d_in[4];
    float* out = (float*)d_out;
    unsigned short* wTf = (unsigned short*)d_ws;      // 160*512*2 = 160 KB

    prep_wT<<<160, 64, 0, stream>>>(w1_s, w1_v, wTf);
    ndr_mfma_kernel<<<NT_ROW, 256, 0, stream>>>(x, wTf, w2_s, w2_v, out);
}

// Round 17
// 101.548 us; speedup vs baseline: 1.4598x; 1.4598x over previous
//
#include <hip/hip_runtime.h>
#include <hip/hip_bf16.h>
#include <math.h>

#define N_ROWS  100000
#define NT_ROW  6250            // 16-row MFMA tiles, exact

typedef __attribute__((ext_vector_type(8))) short bf16x8;   // 4 VGPR A/B frag
typedef __attribute__((ext_vector_type(4))) float f32x4;    // C/D frag

__device__ __forceinline__ float silu_f(float v) {
    return v * (1.0f / (1.0f + __expf(-v)));
}
__device__ __forceinline__ short f2bf(float f) {
    union { __hip_bfloat16 h; short s; } u;
    u.h = __float2bfloat16(f);          // RNE convert
    return u.s;
}
// async global->LDS with NON-TEMPORAL policy (aux=2 = SLC/NT): x is a
// zero-reuse stream; no-allocate keeps L2 for the B weights.
__device__ __forceinline__ void stage16nt(const float* g, float* l) {
    __builtin_amdgcn_global_load_lds(
        (const __attribute__((address_space(1))) unsigned int*)g,
        (__attribute__((address_space(3))) unsigned int*)l,
        16, 0, 2);
}

// ---- pre-kernel: fragment-packed weights (unchanged, verified) -------------
// wTf[(t*8+p)*1024 B + lane*16 B] = B-fragment for col-tile t, K-pass p.
__global__ __launch_bounds__(64)
void prep_wT(const float* __restrict__ w1_s, const float* __restrict__ w1_v,
             unsigned short* __restrict__ wTf)
{
    const int tp = blockIdx.x;               // 0..159 = t*8 + p
    const int t = tp >> 3, p = tp & 7;
    const int lane = threadIdx.x;            // 0..63
    const int l15 = lane & 15, lq = lane >> 4;
    const float* src  = (t < 8) ? w1_s : w1_v;
    const int    strd = (t < 8) ? 128 : 64;
    const int    scol = (t < 8) ? (t * 16 + l15) : (((t - 8) & 3) * 16 + l15);
    const int    k0   = 32 * p + 8 * lq;
    unsigned short o[8];
    #pragma unroll
    for (int e = 0; e < 8; ++e)
        o[e] = (unsigned short)f2bf(src[(k0 + e) * strd + scol]);
    *(ushort4*)(wTf + (size_t)tp * 512 + lane * 8)     = make_ushort4(o[0], o[1], o[2], o[3]);
    *(ushort4*)(wTf + (size_t)tp * 512 + lane * 8 + 4) = make_ushort4(o[4], o[5], o[6], o[7]);
}

// ---- main kernel: r11 structure (109 µs best) + NT on x stages -------------
// 1 wave = 16 rows x 320 cols; wave-private 2x8KB LDS dbuf, no barriers.
__global__ __launch_bounds__(256, 2)
void ndr_mfma_kernel(const float* __restrict__ x,
                     const unsigned short* __restrict__ wTf,
                     const float* __restrict__ w2_s,
                     const float* __restrict__ w2_v,
                     float* __restrict__ out)
{
    __shared__ float lds[2][4][2048];        // [buf][wave][16*128 floats] = 64 KB

    const int lane = threadIdx.x & 63;
    const int wid  = threadIdx.x >> 6;
    const int rt   = blockIdx.x * 4 + wid;
    if (rt >= NT_ROW) return;                // no barriers anywhere -> safe
    const int l15 = lane & 15, lq = lane >> 4;
    const long long n0 = (long long)rt * 16;

    // --- staging map (constant across passes) ---
    // instr j covers rows 2j (lanes 0-31), 2j+1 (lanes 32-63); slot = lane&31.
    const int sub = lane >> 5, slot = lane & 31;
    const float* sp[8];                      // per-j global src for pass 0
    int sstep[8];                            // float advance per pass
    #pragma unroll
    for (int j = 0; j < 8; ++j) {
        const int row = 2 * j + sub;
        const int g   = slot ^ (row & 7);    // inverse-swizzled source segment
        const int isxs = (g < 8);
        const int f0  = isxs ? 4 * g : 256 + 4 * (g - 8);
        sstep[j] = isxs ? 32 : 96;
        sp[j] = x + (n0 + row) * 1024 + f0;
    }

    f32x4 acc[20];
    #pragma unroll
    for (int t = 0; t < 20; ++t) acc[t] = (f32x4){0.f, 0.f, 0.f, 0.f};

    const char* wbase = (const char*)wTf + lane * 16;

    // --- prologue: stage pass 0 -> buf0, pass 1 -> buf1 ---
    #pragma unroll
    for (int j = 0; j < 8; ++j) stage16nt(sp[j],            &lds[0][wid][j * 256]);
    #pragma unroll
    for (int j = 0; j < 8; ++j) stage16nt(sp[j] + sstep[j], &lds[1][wid][j * 256]);

    const int r7 = l15 & 7;
    const float* rb0 = &lds[0][wid][l15 * 128];
    const float* rb1 = &lds[1][wid][l15 * 128];

    #pragma unroll 1
    for (int p = 0; p < 8; ++p) {
        // buf[p&1] ready when everything older than the newest 8 stages landed
        if (p < 7) asm volatile("s_waitcnt vmcnt(8)" ::: "memory");
        else       asm volatile("s_waitcnt vmcnt(0)" ::: "memory");

        const float* rb = (p & 1) ? rb1 : rb0;
        // xs: segs 2lq, 2lq+1 ; xv: segs 8+6lq..8+6lq+5 (slot = seg ^ r7)
        float4 s0 = *(const float4*)(rb + 4 * (( 2 * lq     ) ^ r7));
        float4 s1 = *(const float4*)(rb + 4 * (( 2 * lq + 1 ) ^ r7));
        float4 v0 = *(const float4*)(rb + 4 * ((8 + 6 * lq + 0) ^ r7));
        float4 v1 = *(const float4*)(rb + 4 * ((8 + 6 * lq + 1) ^ r7));
        float4 v2 = *(const float4*)(rb + 4 * ((8 + 6 * lq + 2) ^ r7));
        float4 v3 = *(const float4*)(rb + 4 * ((8 + 6 * lq + 3) ^ r7));
        float4 v4 = *(const float4*)(rb + 4 * ((8 + 6 * lq + 4) ^ r7));
        float4 v5 = *(const float4*)(rb + 4 * ((8 + 6 * lq + 5) ^ r7));

        const float xs[8]  = {s0.x, s0.y, s0.z, s0.w, s1.x, s1.y, s1.z, s1.w};
        const float xv[24] = {v0.x, v0.y, v0.z, v0.w, v1.x, v1.y, v1.z, v1.w,
                              v2.x, v2.y, v2.z, v2.w, v3.x, v3.y, v3.z, v3.w,
                              v4.x, v4.y, v4.z, v4.w, v5.x, v5.y, v5.z, v5.w};
        bf16x8 a_s, a_v0, a_v1, a_v2;        // A[row=l15][k=32p+8lq+e]
        #pragma unroll
        for (int e = 0; e < 8; ++e) {
            a_s[e]  = f2bf(xs[e]);
            a_v0[e] = f2bf(xv[3 * e + 0]);
            a_v1[e] = f2bf(xv[3 * e + 1]);
            a_v2[e] = f2bf(xv[3 * e + 2]);
        }

        // B loads BEFORE the stage issue, so in-flight stages stay newest in
        // vmcnt order (MFMA waits never drain them).
        bf16x8 bf[20];
        #pragma unroll
        for (int t = 0; t < 20; ++t)
            bf[t] = *(const bf16x8*)(wbase + (size_t)p * 1024 + (size_t)t * 8192);

        // overwrite the just-consumed buffer with pass p+2 (LDS reads fenced)
        if (p + 2 < 8) {
            asm volatile("s_waitcnt lgkmcnt(0)" ::: "memory");
            #pragma unroll
            for (int j = 0; j < 8; ++j)
                stage16nt(sp[j] + (p + 2) * sstep[j], &lds[p & 1][wid][j * 256]);
        }

        #pragma unroll
        for (int t = 0; t < 20; ++t) {
            const bf16x8 a = (t < 8) ? a_s : (t < 12) ? a_v0
                            : (t < 16) ? a_v1 : a_v2;
            acc[t] = __builtin_amdgcn_mfma_f32_16x16x32_bf16(a, bf[t], acc[t], 0, 0, 0);
        }
    }

    // ---- epilogue: silu-gate + layer 2 in fp32 (unchanged, verified) -------
    const float inv_in = 0.0625f, inv_h = 0.125f;
    float w2sv[4], w2vv[4];
    #pragma unroll
    for (int u = 0; u < 4; ++u) {
        w2sv[u] = w2_s[u * 16 + l15];
        w2vv[u] = w2_v[u * 16 + l15];
    }
    #pragma unroll
    for (int j = 0; j < 4; ++j) {
        float ps = 0.f, pv0 = 0.f, pv1 = 0.f, pv2 = 0.f;
        #pragma unroll
        for (int u = 0; u < 4; ++u) {
            float hs = acc[u][j]     * inv_in;
            float hg = acc[4 + u][j] * inv_in;
            float gg = silu_f(hg);
            ps  += silu_f(hs) * w2sv[u];
            pv0 += gg * (acc[8  + u][j] * inv_in) * w2vv[u];
            pv1 += gg * (acc[12 + u][j] * inv_in) * w2vv[u];
            pv2 += gg * (acc[16 + u][j] * inv_in) * w2vv[u];
        }
        #pragma unroll
        for (int off = 1; off <= 8; off <<= 1) {
            ps  += __shfl_xor(ps,  off, 64);
            pv0 += __shfl_xor(pv0, off, 64);
            pv1 += __shfl_xor(pv1, off, 64);
            pv2 += __shfl_xor(pv2, off, 64);
        }
        if (l15 == 0) {
            long long n = n0 + lq * 4 + j;
            *(float4*)(out + n * 4) =
                make_float4(ps * inv_h, pv0 * inv_h, pv1 * inv_h, pv2 * inv_h);
        }
    }
}

extern "C" void kernel_launch(void* const* d_in, const int* in_sizes, int n_in,
                              void* d_out, int out_size, void* d_ws, size_t ws_size,
                              hipStream_t stream) {
    const float* x    = (const float*)d_in[0];
    const float* w1_s = (const float*)d_in[1];
    const float* w1_v = (const float*)d_in[2];
    const float* w2_s = (const float*)d_in[3];
    const float* w2_v = (const float*)d_in[4];
    float* out = (float*)d_out;
    unsigned short* wTf = (unsigned short*)d_ws;      // 160*512*2 = 160 KB

    prep_wT<<<160, 64, 0, stream>>>(w1_s, w1_v, wTf);
    int blocks = (NT_ROW + 3) / 4;                    // 1563; tail waves exit
    ndr_mfma_kernel<<<blocks, 256, 0, stream>>>(x, wTf, w2_s, w2_v, out);
}